// Round 7
// baseline (166.046 us; speedup 1.0000x reference)
//
#include <hip/hip_runtime.h>
#include <hip/hip_bf16.h>

typedef int   i32x4  __attribute__((ext_vector_type(4)));
typedef int   i32x8  __attribute__((ext_vector_type(8)));
typedef float f32x16 __attribute__((ext_vector_type(16)));

__device__ inline void gload_lds16(const void* g, void* l) {
  __builtin_amdgcn_global_load_lds((const __attribute__((address_space(1))) void*)g,
                                   (__attribute__((address_space(3))) void*)l, 16, 0, 0);
}
__device__ inline void gload_lds4(const void* g, void* l) {
  __builtin_amdgcn_global_load_lds((const __attribute__((address_space(1))) void*)g,
                                   (__attribute__((address_space(3))) void*)l, 4, 0, 0);
}
__device__ inline i32x8 pad8(i32x4 v) {
  i32x8 r;
  r[0] = v[0]; r[1] = v[1]; r[2] = v[2]; r[3] = v[3];
  r[4] = 0; r[5] = 0; r[6] = 0; r[7] = 0;
  return r;
}

// ------------- Fused quantization: Hadamard(32) rotate + MXFP4 pack (x and w in one grid) ---
// Blocks [0, xblocks) process x; the rest process w. All branches block-uniform.
// Grid is exact (n_groups % 256 == 0 for both sides).
__global__ __launch_bounds__(256) void quant_fused(const float* __restrict__ x,
                                                   const float* __restrict__ wt,
                                                   unsigned char* __restrict__ xq,
                                                   unsigned char* __restrict__ xsc,
                                                   unsigned char* __restrict__ wq,
                                                   unsigned char* __restrict__ wsc,
                                                   const float* __restrict__ ags,
                                                   const float* __restrict__ wgs,
                                                   int xg, int Mrows, int Nrows, int kg) {
  const int first = blockIdx.x * 256;
  const bool isX = first < xg;
  const float* in        = isX ? x   : wt;
  unsigned char* outq    = isX ? xq  : wq;
  unsigned char* outsc   = isX ? xsc : wsc;
  const float gs         = isX ? ags[0] : wgs[0];
  const int rows         = isX ? Mrows : Nrows;
  const int base         = isX ? first : first - xg;
  const int g = base + threadIdx.x;
  const int r = g / kg, j = g - r * kg;

  float t[32];
  const float4* p4 = (const float4*)(in + (size_t)g * 32);
#pragma unroll
  for (int i = 0; i < 8; ++i) {
    float4 v4 = p4[i];
    t[4 * i + 0] = v4.x; t[4 * i + 1] = v4.y;
    t[4 * i + 2] = v4.z; t[4 * i + 3] = v4.w;
  }
#pragma unroll
  for (int s = 0; s < 5; ++s) {
    const int hh = 1 << s;
#pragma unroll
    for (int i = 0; i < 32; ++i) {
      if ((i & hh) == 0) {
        float a = t[i], b = t[i + hh];
        t[i] = a + b;
        t[i + hh] = a - b;
      }
    }
  }

  const float c = 0.17677669529663687f;  // 32^-0.5
  float v[32];
  float am = 0.0f;
#pragma unroll
  for (int i = 0; i < 32; ++i) {
    float vi = (t[i] * c) * gs;
    v[i] = vi;
    am = fmaxf(am, fabsf(vi));
  }

  float a6 = am / 6.0f;
  int ex;
  float mant = frexpf(a6, &ex);
  int e = (mant == 0.5f) ? ex - 1 : ex;  // exact ceil(log2(a6))
  if (e < -127) e = -127;
  if (e > 127) e = 127;
  float inv_s = ldexpf(1.0f, -e);

  unsigned int dw[4] = {0u, 0u, 0u, 0u};
#pragma unroll
  for (int i = 0; i < 32; ++i) {
    float u = v[i] * inv_s;
    float au = fabsf(u);
    int idx = (au > 0.25f) + (au > 0.75f) + (au > 1.25f) + (au > 1.75f)
            + (au > 2.5f) + (au > 3.5f) + (au > 5.0f);
    int code = idx | ((u < 0.0f) ? 8 : 0);
    dw[i >> 3] |= (unsigned)code << ((i & 7) * 4);
  }
  i32x4 packed;
  packed[0] = (int)dw[0]; packed[1] = (int)dw[1];
  packed[2] = (int)dw[2]; packed[3] = (int)dw[3];
  *(i32x4*)(outq + (size_t)r * ((size_t)kg * 16) + (size_t)j * 16) = packed;

  // scale byte: layout [step s][row][8B], byte p = h*4 + kk for block j0 = 2*kk + h
  int s = j >> 3, j0 = j & 7;
  int p = ((j0 & 1) << 2) | (j0 >> 1);
  if (kg == 128) {
    __shared__ unsigned char sl[256];  // [16 steps][2 rows][8B]
    sl[(s << 4) | ((r & 1) << 3) | p] = (unsigned char)(e + 127);
    __syncthreads();
    if (threadIdx.x < 64) {
      int si = threadIdx.x >> 2, wd = threadIdx.x & 3;
      unsigned int vv = *(const unsigned int*)&sl[(si << 4) | (wd << 2)];
      size_t r0 = (size_t)(base / 128);
      *(unsigned int*)(outsc + ((size_t)si * rows + r0) * 8 + (wd << 2)) = vv;
    }
  } else {
    outsc[((size_t)s * rows + r) * 8 + p] = (unsigned char)(e + 127);
  }
}

// ---------------- 128x128 MX-FP4 GEMM, 2 blocks/CU, register-dbuf fragments ----------
// 4 waves (2M x 2N), BK=256, LDS dbuf + REGISTER dbuf: tile t's MFMA (reg set cur)
// overlaps tile t+1's ds_reads (reg set nxt). One vmcnt(6)+barrier and one
// lgkmcnt(0)+barrier per K-tile. Ledger: 6 VMEM/tile-set, steady queue
// [t+1^6, t+2^6] at tile top -> VM6 drains t+1 exactly.

#define STAGE(mb, kt, h, ldsHalf) do {                                               \
    const unsigned char* _s = (mb) + (size_t)((h)*64 + (w << 3) + (l >> 3)) * KB2    \
                      + (size_t)(kt) * 128 + (size_t)csw * 16;                       \
    gload_lds16(_s, (unsigned char*)(ldsHalf) + (w << 10));                          \
    gload_lds16(_s + ((size_t)KB2 << 5), (unsigned char*)(ldsHalf) + (w << 10) + 4096); \
  } while (0)

#define STAGE_ASC(kt, bf) gload_lds4(AscG + ((size_t)(kt) * M + brow) * 8 + (tid << 2), \
                                     (unsigned char*)&asc[bf][0] + (w << 8))
#define STAGE_BSC(kt, bf) gload_lds4(BscG + ((size_t)(kt) * N + bcol) * 8 + (tid << 2), \
                                     (unsigned char*)&bsc[bf][0] + (w << 8))

#define STAGESET(kt, bf) do {                                                        \
    STAGE(Ab, kt, 0, &lds[bf][0][0][0]); STAGE(Ab, kt, 1, &lds[bf][0][1][0]);        \
    STAGE_ASC(kt, bf);                                                               \
    STAGE(Bb, kt, 0, &lds[bf][1][0][0]); STAGE(Bb, kt, 1, &lds[bf][1][1][0]);        \
    STAGE_BSC(kt, bf);                                                               \
  } while (0)

#define READFRAGS(bf, AF, BF, SA, SB) do {                                           \
    const unsigned char* _bb = &lds[bf][1][0][0];                                    \
    _Pragma("unroll")                                                                \
    for (int nt = 0; nt < 2; ++nt) {                                                 \
      int row = wn * 64 + nt * 32 + (l & 31);                                        \
      int xr = row & 7;                                                              \
      _Pragma("unroll")                                                              \
      for (int kk = 0; kk < 4; ++kk)                                                 \
        BF[nt][kk] = *(const i32x4*)(_bb + row * 128 + (((kk * 2 + h) ^ xr) << 4));  \
      SB[nt] = *(const int*)((const unsigned char*)&bsc[bf][0] + row * 8 + h * 4);   \
    }                                                                                \
    const unsigned char* _ab = &lds[bf][0][0][0];                                    \
    _Pragma("unroll")                                                                \
    for (int mt = 0; mt < 2; ++mt) {                                                 \
      int row = wm * 64 + mt * 32 + (l & 31);                                        \
      int xr = row & 7;                                                              \
      _Pragma("unroll")                                                              \
      for (int kk = 0; kk < 4; ++kk)                                                 \
        AF[mt][kk] = *(const i32x4*)(_ab + row * 128 + (((kk * 2 + h) ^ xr) << 4));  \
      SA[mt] = *(const int*)((const unsigned char*)&asc[bf][0] + row * 8 + h * 4);   \
    }                                                                                \
  } while (0)

#define MF1(AF, BF, SA, SB, mt, nt, kk)                                              \
  acc[mt][nt] = __builtin_amdgcn_mfma_scale_f32_32x32x64_f8f6f4(                     \
      pad8(AF[mt][kk]), pad8(BF[nt][kk]), acc[mt][nt], 4, 4, kk, SA[mt], kk, SB[nt]);

#define MFMAQ_ALL(AF, BF, SA, SB) do {                                               \
    __builtin_amdgcn_s_setprio(1);                                                   \
    MF1(AF, BF, SA, SB, 0, 0, 0) MF1(AF, BF, SA, SB, 0, 1, 0)                        \
    MF1(AF, BF, SA, SB, 1, 0, 0) MF1(AF, BF, SA, SB, 1, 1, 0)                        \
    MF1(AF, BF, SA, SB, 0, 0, 1) MF1(AF, BF, SA, SB, 0, 1, 1)                        \
    MF1(AF, BF, SA, SB, 1, 0, 1) MF1(AF, BF, SA, SB, 1, 1, 1)                        \
    MF1(AF, BF, SA, SB, 0, 0, 2) MF1(AF, BF, SA, SB, 0, 1, 2)                        \
    MF1(AF, BF, SA, SB, 1, 0, 2) MF1(AF, BF, SA, SB, 1, 1, 2)                        \
    MF1(AF, BF, SA, SB, 0, 0, 3) MF1(AF, BF, SA, SB, 0, 1, 3)                        \
    MF1(AF, BF, SA, SB, 1, 0, 3) MF1(AF, BF, SA, SB, 1, 1, 3)                        \
    __builtin_amdgcn_s_setprio(0);                                                   \
  } while (0)

#define LGKM0() do { asm volatile("s_waitcnt lgkmcnt(0)" ::: "memory");              \
    __builtin_amdgcn_sched_barrier(0); } while (0)
#define VM6()  asm volatile("s_waitcnt vmcnt(6)" ::: "memory")

__global__ __launch_bounds__(256, 2) void gemm128_fp4(const unsigned char* __restrict__ Aq,
                                                      const unsigned char* __restrict__ Bq,
                                                      const unsigned char* __restrict__ AscG,
                                                      const unsigned char* __restrict__ BscG,
                                                      float* __restrict__ C,
                                                      const float* __restrict__ bias,
                                                      const float* __restrict__ gsx,
                                                      const float* __restrict__ gsw,
                                                      int M, int N, int K) {
  __shared__ __align__(16) unsigned char lds[2][2][2][8192];  // [buf][A/B][half][64 rows x 128B]
  __shared__ __align__(16) unsigned char asc[2][1024];        // [buf][128 rows x 8B]
  __shared__ __align__(16) unsigned char bsc[2][1024];

  const int tid = threadIdx.x;
  const int w = tid >> 6, l = tid & 63;
  const int wm = w >> 1, wn = w & 1;
  const int h = l >> 5;
  const int csw = (l & 7) ^ (l >> 3);  // inverse-swizzled source chunk
  const int KB2 = K >> 1;              // bytes per row

  // T1 + L2 supertiling (proven: FETCH 148->70MB): XCD band + 8x8 supertiles.
  const int ntn = N >> 7;
  const int nwg = gridDim.x;
  int r_t, c_t;
  {
    int bid = blockIdx.x;
    if ((nwg & 7) == 0) {
      int x = bid & 7, o = bid >> 3, cpx = nwg >> 3;
      int rpx = cpx / ntn;
      if ((ntn & 7) == 0 && rpx > 0 && (cpx % ntn) == 0) {
        int g8 = o & 7, rr = (o >> 3) % rpx, ss = o / (8 * rpx);
        r_t = x * rpx + rr;
        c_t = ss * 8 + g8;
      } else {
        int lin = x * cpx + o;
        r_t = lin / ntn; c_t = lin % ntn;
      }
    } else {
      r_t = bid / ntn; c_t = bid % ntn;
    }
  }
  const size_t brow = (size_t)r_t * 128;
  const size_t bcol = (size_t)c_t * 128;

  const unsigned char* Ab = Aq + brow * (size_t)KB2;
  const unsigned char* Bb = Bq + bcol * (size_t)KB2;

  f32x16 acc[2][2];
#pragma unroll
  for (int m = 0; m < 2; ++m)
#pragma unroll
    for (int n = 0; n < 2; ++n)
#pragma unroll
      for (int r = 0; r < 16; ++r) acc[m][n][r] = 0.0f;

  i32x4 afA[2][4], bfrA[2][4];  int saA[2], sbA[2];
  i32x4 afB[2][4], bfrB[2][4];  int saB[2], sbB[2];

  const int nkt = K / 256;       // 16 (even)

  // Prologue: stage tile0->buf0 (6), tile1->buf1 (6); drain tile0; read its frags.
  STAGESET(0, 0);
  STAGESET(1, 1);
  VM6();
  __builtin_amdgcn_s_barrier();
  READFRAGS(0, afA, bfrA, saA, sbA);
  LGKM0();
  __builtin_amdgcn_s_barrier();

  for (int t = 0; t < nkt; t += 2) {
    const int t2 = (t + 2 < nkt) ? t + 2 : nkt - 1;  // clamped over-stage: dead data
    const int t3 = (t + 3 < nkt) ? t + 3 : nkt - 1;

    // tile t (even, regs A): stage t+2 -> buf0 (its frags in regsA, barriered);
    // wait t+1 landed; read t+1 frags (regs B) overlapping MFMA on regs A.
    STAGESET(t2, 0);
    VM6();
    __builtin_amdgcn_s_barrier();
    READFRAGS(1, afB, bfrB, saB, sbB);
    MFMAQ_ALL(afA, bfrA, saA, sbA);
    LGKM0();
    __builtin_amdgcn_s_barrier();

    // tile t+1 (odd, regs B)
    STAGESET(t3, 1);
    VM6();
    __builtin_amdgcn_s_barrier();
    READFRAGS(0, afA, bfrA, saA, sbA);
    MFMAQ_ALL(afB, bfrB, saB, sbB);
    LGKM0();
    __builtin_amdgcn_s_barrier();
  }

  const float inv = 1.0f / (gsx[0] * gsw[0]);
#pragma unroll
  for (int nt = 0; nt < 2; ++nt) {
    const int col = (int)bcol + wn * 64 + nt * 32 + (l & 31);
    const float bv = bias[col];
#pragma unroll
    for (int mt = 0; mt < 2; ++mt) {
      const size_t rbase = brow + (size_t)(wm * 64 + mt * 32 + 4 * h);
#pragma unroll
      for (int r = 0; r < 16; ++r) {
        const size_t row = rbase + (r & 3) + 8 * (r >> 2);
        C[row * (size_t)N + col] = acc[mt][nt][r] * inv + bv;
      }
    }
  }
}

extern "C" void kernel_launch(void* const* d_in, const int* in_sizes, int n_in,
                              void* d_out, int out_size, void* d_ws, size_t ws_size,
                              hipStream_t stream) {
  const float* x    = (const float*)d_in[0];
  const float* wgt  = (const float*)d_in[1];
  const float* bias = (const float*)d_in[2];
  const float* wgs  = (const float*)d_in[4];
  const float* ags  = (const float*)d_in[5];

  const int N = in_sizes[2];            // 4096
  const int K = in_sizes[1] / N;        // 4096
  const int M = in_sizes[0] / K;        // 8192
  const int kg = K / 32;                // 128

  unsigned char* aq  = (unsigned char*)d_ws;
  unsigned char* bq  = aq + (size_t)M * (K / 2);
  unsigned char* asc = bq + (size_t)N * (K / 2);
  unsigned char* bsc = asc + (size_t)M * kg;

  const int xg = in_sizes[0] / 32;
  const int wg = in_sizes[1] / 32;
  quant_fused<<<dim3((xg + wg) / 256), dim3(256), 0, stream>>>(
      x, wgt, aq, asc, bq, bsc, ags, wgs, xg, M, N, kg);

  dim3 grid((M / 128) * (N / 128));
  gemm128_fp4<<<grid, dim3(256), 0, stream>>>(aq, bq, asc, bsc, (float*)d_out, bias,
                                              ags, wgs, M, N, K);
}